// Round 7
// baseline (966.557 us; speedup 1.0000x reference)
//
#include <hip/hip_runtime.h>
#include <math.h>

#define BB 128
#define NTOK 197
#define CC 768
#define HH 12
#define HD 64
#define HIDN 3072
#define NP 177
#define NPATCH 196
#define THRK 19
#define MR (BB*NP)     // 22656 real rows
#define MRP 22784      // padded to 89*256 for the 256-tile GEMM

using short8 = __attribute__((ext_vector_type(8))) short;
using f32x4  = __attribute__((ext_vector_type(4))) float;

__device__ __forceinline__ unsigned short f2b(float f){
  unsigned u = __builtin_bit_cast(unsigned, f);
  u += 0x7fffu + ((u >> 16) & 1u);
  return (unsigned short)(u >> 16);
}

// gelu(v) = 0.5 v (1 + erf(v/sqrt2)), erf via A&S 7.1.26 (|err|<=1.5e-7) + __expf
__device__ __forceinline__ float fast_gelu(float v){
  float u = v * 0.70710678118654752f;
  float a = fabsf(u);
  float t = 1.0f / fmaf(0.3275911f, a, 1.0f);
  float p = fmaf(1.061405429f, t, -1.453152027f);
  p = fmaf(p, t, 1.421413741f);
  p = fmaf(p, t, -0.284496736f);
  p = fmaf(p, t, 0.254829592f);
  p = p * t;
  float e = __expf(-a*a);
  float erfu = copysignf(1.0f - p*e, u);
  return 0.5f * v * (1.0f + erfu);
}

__device__ __forceinline__ void gload16(const void* src, void* lds){
  __builtin_amdgcn_global_load_lds(
      (const __attribute__((address_space(1))) unsigned int*)src,
      (__attribute__((address_space(3))) unsigned int*)lds,
      16, 0, 0);
}

// ---------- fused transpose+cvt: W[K][N] f32 -> Wt[N][K] bf16 ----------
__global__ void tcvt_kernel(const float* __restrict__ in, unsigned short* __restrict__ out, int K, int N){
  __shared__ float tile[64][65];
  int n0 = blockIdx.x*64, k0 = blockIdx.y*64;
  int t = threadIdx.x;
  int r = t >> 6, c = t & 63;
  #pragma unroll
  for (int i = 0; i < 16; ++i)
    tile[r + i*4][c] = in[(size_t)(k0 + r + i*4)*N + n0 + c];
  __syncthreads();
  #pragma unroll
  for (int i = 0; i < 16; ++i)
    out[(size_t)(n0 + r + i*4)*K + k0 + c] = f2b(tile[c][r + i*4]);
}

// ---------- scoring path (fp64 accum: selection boundary must not flip) ----------
__global__ void q0_kernel(const float* __restrict__ x, const float* __restrict__ Wqkv, float* __restrict__ q0){
  int b = blockIdx.x, t = threadIdx.x;
  int c = blockIdx.y*256 + t;
  __shared__ float xs[CC];
  for (int j = t; j < CC; j += 256) xs[j] = x[(size_t)b*NTOK*CC + j];
  __syncthreads();
  double acc = 0.0;
  for (int j = 0; j < CC; ++j) acc = fma((double)xs[j], (double)Wqkv[(size_t)j*(3*CC) + c], acc);
  q0[b*CC + c] = (float)acc;
}

// wave-per-row, lane-strided (coalesced) reads
__global__ void wvec_kernel(const float* __restrict__ Wqkv, const float* __restrict__ q0, float* __restrict__ wv){
  int b = blockIdx.x;
  int j = blockIdx.y*4 + (threadIdx.x >> 6);
  int l = threadIdx.x & 63;
  const float* row = Wqkv + (size_t)j*(3*CC) + CC;  // Wk column block
  const float* qs = q0 + b*CC;
  double acc = 0.0;
  for (int c = l; c < CC; c += 64) acc = fma((double)row[c], (double)qs[c], acc);
  for (int off = 32; off; off >>= 1) acc += __shfl_down(acc, off);
  if (l == 0) wv[b*CC + j] = (float)acc;
}

__global__ void score_kernel(const float* __restrict__ x, const float* __restrict__ wv, float* __restrict__ sc){
  int m = blockIdx.x, b = blockIdx.y, l = threadIdx.x;  // one wave per (b,m)
  const float* xr = x + ((size_t)b*NTOK + 1 + m)*CC;
  const float* wr = wv + b*CC;
  double acc = 0.0;
  for (int c = l; c < CC; c += 64) acc = fma((double)xr[c], (double)wr[c], acc);
  for (int off = 32; off; off >>= 1) acc += __shfl_down(acc, off);
  if (l == 0) sc[b*NPATCH + m] = (float)(acc * (1.0/12.0));
}

// stable rank (== argsort(argsort) with stable ties), keep rank>19, compact in order
__global__ void select_kernel(const float* __restrict__ sc, int* __restrict__ tok){
  int b = blockIdx.x, t = threadIdx.x;
  __shared__ float s[NPATCH];
  __shared__ int kp[NPATCH];
  for (int m = t; m < NPATCH; m += 256) s[m] = sc[b*NPATCH + m];
  __syncthreads();
  for (int m = t; m < NPATCH; m += 256){
    float v = s[m]; int rank = 0;
    for (int j = 0; j < NPATCH; ++j){
      float u = s[j];
      rank += (u < v) || (u == v && j < m);
    }
    kp[m] = (rank > THRK) ? 1 : 0;
  }
  __syncthreads();
  for (int m = t; m < NPATCH; m += 256){
    if (kp[m]){
      int pos = 0;
      for (int j = 0; j < m; ++j) pos += kp[j];
      tok[b*NP + 1 + pos] = m + 1;
    }
  }
  if (t == 0) tok[b*NP] = 0;
}

__global__ void gather_kernel(const float* __restrict__ x, const int* __restrict__ tok, float* __restrict__ xk){
  int i = blockIdx.x, b = blockIdx.y, t = threadIdx.x;
  int src = tok[b*NP + i];
  const float* xr = x + ((size_t)b*NTOK + src)*CC;
  float* o = xk + ((size_t)b*NP + i)*CC;
  for (int c = t; c < CC; c += 256) o[c] = xr[c] * (1.0f/0.9f);
}

// ---------- LayerNorm: fp32 in -> bf16 out ----------
__global__ void ln_kernel(const float* __restrict__ in, const float* __restrict__ g,
                          const float* __restrict__ bt, unsigned short* __restrict__ out){
  int row = blockIdx.x, t = threadIdx.x;
  const float* xr = in + (size_t)row*CC;
  float v0 = xr[t], v1 = xr[t+256], v2 = xr[t+512];
  float s = v0+v1+v2, ss = v0*v0+v1*v1+v2*v2;
  for (int off = 32; off; off >>= 1){ s += __shfl_down(s, off); ss += __shfl_down(ss, off); }
  __shared__ float red[8];
  int wid = t >> 6, lane = t & 63;
  if (lane == 0){ red[wid] = s; red[4+wid] = ss; }
  __syncthreads();
  if (t == 0){
    float S = red[0]+red[1]+red[2]+red[3], SS = red[4]+red[5]+red[6]+red[7];
    float mean = S * (1.0f/CC);
    float var = SS * (1.0f/CC) - mean*mean;
    red[0] = mean; red[1] = rsqrtf(var + 1e-5f);
  }
  __syncthreads();
  float mean = red[0], rstd = red[1];
  unsigned short* orow = out + (size_t)row*CC;
  orow[t]     = f2b((v0-mean)*rstd*g[t]     + bt[t]);
  orow[t+256] = f2b((v1-mean)*rstd*g[t+256] + bt[t+256]);
  orow[t+512] = f2b((v2-mean)*rstd*g[t+512] + bt[t+512]);
}

// ---------- GEMM: 256x256 tile, BK=32, 3-buffer counted-vmcnt pipeline ----------
// A [MRP][K] bf16 row-major (rows >= Mreal are padding), Bt [N][K] bf16 row-major.
// 8 waves (2M x 4N), per-wave 128x64 output. LDS 96KB (3 bufs x (A 16KB + B 16KB)).
// T2 swizzle: LDS chunk (row,k16) holds global chunk (row, k16 ^ ((row>>1)&3));
// gload_lds dest stays lane-linear, source pre-swizzled, ds_read swizzled (rule #21).
// Window-end: s_waitcnt vmcnt(4) (counted, not a drain) + raw s_barrier.
// EPI: 0 = plain -> bf16 ; 1/3 = +bias +res -> f32 (row<Mreal guarded) ; 2 = +bias, gelu -> bf16
template<int EPI>
__global__ __launch_bounds__(512, 2) void gemm256(
    const unsigned short* __restrict__ A, const unsigned short* __restrict__ Bt,
    const float* __restrict__ bias, const float* __restrict__ res, void* __restrict__ outp,
    int Mreal, int N, int K)
{
  __shared__ __align__(16) short lds[3*16384];
  // bijective XCD swizzle (m204)
  int nwg = gridDim.x, o = blockIdx.x;
  int q = nwg >> 3, rr = nwg & 7;
  int xcd = o & 7, seq = o >> 3;
  int wg = (xcd < rr) ? xcd*(q+1) + seq : rr*(q+1) + (xcd - rr)*q + seq;
  int nx = N >> 8;
  int m0 = (wg / nx) << 8, n0 = (wg % nx) << 8;

  int t = threadIdx.x, wid = t >> 6, l = t & 63;
  int wr = wid >> 2, wc = wid & 3;

  f32x4 acc[8][4] = {};
  int nt = K >> 5;

  auto stage = [&](int kti){
    int kt = kti << 5;
    short* buf = &lds[(kti % 3) * 16384];
    #pragma unroll
    for (int h = 0; h < 2; ++h){
      int c = h*512 + t;
      int row = c >> 2;
      int k16 = (c & 3) ^ ((row >> 1) & 3);     // inverse-swizzled source chunk
      short* db = buf + (size_t)(h*512 + wid*64)*8;   // wave-uniform dest base
      gload16(A  + (size_t)(m0 + row)*K + kt + k16*8, db);
      gload16(Bt + (size_t)(n0 + row)*K + kt + k16*8, db + 8192);
    }
  };

  // prologue: tiles 0,1 in flight; wait for tile 0 (vmcnt(4) leaves tile 1 flying)
  stage(0); stage(1);
  asm volatile("s_waitcnt vmcnt(4)" ::: "memory");
  __builtin_amdgcn_s_barrier();
  asm volatile("" ::: "memory");

  for (int ti = 0; ti < nt; ++ti){
    if (ti + 2 < nt) stage(ti + 2);            // issue 2 windows ahead
    const short* Abuf = &lds[(ti % 3) * 16384];
    const short* Bbuf = Abuf + 8192;
    short8 bf[4];
    #pragma unroll
    for (int j = 0; j < 4; ++j){
      int row = wc*64 + j*16 + (l & 15);
      int k16 = (l >> 4) ^ ((row >> 1) & 3);   // swizzled read
      bf[j] = *reinterpret_cast<const short8*>(&Bbuf[row*32 + k16*8]);
    }
    __builtin_amdgcn_s_setprio(1);
    #pragma unroll
    for (int i = 0; i < 8; ++i){
      int row = wr*128 + i*16 + (l & 15);
      int k16 = (l >> 4) ^ ((row >> 1) & 3);
      short8 af = *reinterpret_cast<const short8*>(&Abuf[row*32 + k16*8]);
      #pragma unroll
      for (int j = 0; j < 4; ++j)
        acc[i][j] = __builtin_amdgcn_mfma_f32_16x16x32_bf16(af, bf[j], acc[i][j], 0, 0, 0);
    }
    __builtin_amdgcn_s_setprio(0);
    // counted wait: proves tile ti+1 landed (its 4 loads are the oldest); tile ti+2's 4 stay in flight
    if (ti + 2 < nt) asm volatile("s_waitcnt vmcnt(4)" ::: "memory");
    else             asm volatile("s_waitcnt vmcnt(0)" ::: "memory");
    __builtin_amdgcn_s_barrier();
    asm volatile("" ::: "memory");
  }

  #pragma unroll
  for (int i = 0; i < 8; ++i){
    int row0 = m0 + wr*128 + i*16 + (l >> 4)*4;
    #pragma unroll
    for (int j = 0; j < 4; ++j){
      int col = n0 + wc*64 + j*16 + (l & 15);
      #pragma unroll
      for (int r = 0; r < 4; ++r){
        int row = row0 + r;
        float v = acc[i][j][r];
        if (EPI != 0) v += bias[col];
        if (EPI == 2) v = fast_gelu(v);
        if (EPI == 0 || EPI == 2){
          ((unsigned short*)outp)[(size_t)row*N + col] = f2b(v);   // padded-row alloc'd
        } else {
          if (row < Mreal){
            v += res[(size_t)row*N + col];
            ((float*)outp)[(size_t)row*N + col] = v;
          }
        }
      }
    }
  }
}

// ---------- fused attention: QK^T -> softmax -> PV, per (rowblock, head, batch) ----------
__global__ __launch_bounds__(256) void attn_kernel(const unsigned short* __restrict__ qkv2,
                                                   unsigned short* __restrict__ o)
{
  int rt = blockIdx.x, h = blockIdx.y, b = blockIdx.z;
  int t = threadIdx.x, w = t >> 6, l = t & 63;
  __shared__ short Vt[64*192];       // Vt[d][m], m padded to 192
  __shared__ short P[4][16*192];     // per-wave P strip
  for (int idx = t; idx < NP*8; idx += 256){
    int m = idx >> 3, d0 = (idx & 7)*8;
    short8 v = *reinterpret_cast<const short8*>(qkv2 + (size_t)(b*NP+m)*(3*CC) + 2*CC + h*HD + d0);
    #pragma unroll
    for (int j = 0; j < 8; ++j) Vt[(d0+j)*192 + m] = v[j];
  }
  for (int idx = t; idx < 64*15; idx += 256){
    int d = idx/15, m = NP + idx%15;
    Vt[d*192 + m] = 0;
  }
  __syncthreads();
  int nb = rt*64 + w*16;
  int g = l >> 4, c = l & 15;
  int nq = nb + c; if (nq > NP-1) nq = NP-1;
  const unsigned short* qrow = qkv2 + (size_t)(b*NP+nq)*(3*CC) + h*HD + 8*g;
  short8 aq0 = *reinterpret_cast<const short8*>(qrow);
  short8 aq1 = *reinterpret_cast<const short8*>(qrow + 32);
  f32x4 acc[12];
  #pragma unroll
  for (int ct = 0; ct < 12; ++ct){
    int m = ct*16 + c; if (m > NP-1) m = NP-1;
    const unsigned short* krow = qkv2 + (size_t)(b*NP+m)*(3*CC) + CC + h*HD + 8*g;
    short8 bk0 = *reinterpret_cast<const short8*>(krow);
    short8 bk1 = *reinterpret_cast<const short8*>(krow + 32);
    f32x4 a = {};
    a = __builtin_amdgcn_mfma_f32_16x16x32_bf16(aq0, bk0, a, 0, 0, 0);
    a = __builtin_amdgcn_mfma_f32_16x16x32_bf16(aq1, bk1, a, 0, 0, 0);
    acc[ct] = a;
  }
  float mx[4] = {-INFINITY, -INFINITY, -INFINITY, -INFINITY};
  #pragma unroll
  for (int ct = 0; ct < 12; ++ct){
    bool valid = (ct*16 + c) < NP;
    #pragma unroll
    for (int r = 0; r < 4; ++r){
      float v = valid ? acc[ct][r]*0.125f : -INFINITY;
      acc[ct][r] = v;
      mx[r] = fmaxf(mx[r], v);
    }
  }
  #pragma unroll
  for (int off = 1; off < 16; off <<= 1){
    #pragma unroll
    for (int r = 0; r < 4; ++r) mx[r] = fmaxf(mx[r], __shfl_xor(mx[r], off));
  }
  float sm2[4] = {0.f, 0.f, 0.f, 0.f};
  #pragma unroll
  for (int ct = 0; ct < 12; ++ct)
    #pragma unroll
    for (int r = 0; r < 4; ++r){
      float e = __expf(acc[ct][r] - mx[r]);
      acc[ct][r] = e; sm2[r] += e;
    }
  #pragma unroll
  for (int off = 1; off < 16; off <<= 1){
    #pragma unroll
    for (int r = 0; r < 4; ++r) sm2[r] += __shfl_xor(sm2[r], off);
  }
  float inv[4];
  #pragma unroll
  for (int r = 0; r < 4; ++r) inv[r] = 1.0f / sm2[r];
  #pragma unroll
  for (int ct = 0; ct < 12; ++ct)
    #pragma unroll
    for (int r = 0; r < 4; ++r)
      P[w][(4*g + r)*192 + ct*16 + c] = (short)f2b(acc[ct][r]*inv[r]);
  f32x4 acc2[4] = {};
  __builtin_amdgcn_s_setprio(1);
  #pragma unroll
  for (int ks = 0; ks < 6; ++ks){
    short8 pa = *reinterpret_cast<const short8*>(&P[w][c*192 + ks*32 + 8*g]);
    #pragma unroll
    for (int ct2 = 0; ct2 < 4; ++ct2){
      short8 bv = *reinterpret_cast<const short8*>(&Vt[(ct2*16 + c)*192 + ks*32 + 8*g]);
      acc2[ct2] = __builtin_amdgcn_mfma_f32_16x16x32_bf16(pa, bv, acc2[ct2], 0, 0, 0);
    }
  }
  __builtin_amdgcn_s_setprio(0);
  #pragma unroll
  for (int ct2 = 0; ct2 < 4; ++ct2){
    #pragma unroll
    for (int r = 0; r < 4; ++r){
      int n = nb + 4*g + r;
      if (n < NP) o[(size_t)(b*NP+n)*CC + h*HD + ct2*16 + c] = f2b(acc2[ct2][r]);
    }
  }
}

extern "C" void kernel_launch(void* const* d_in, const int* in_sizes, int n_in,
                              void* d_out, int out_size, void* d_ws, size_t ws_size,
                              hipStream_t stream) {
  const float* x     = (const float*)d_in[0];
  const float* ln1g  = (const float*)d_in[1];
  const float* ln1b  = (const float*)d_in[2];
  const float* Wqkv  = (const float*)d_in[3];
  const float* Wproj = (const float*)d_in[4];
  const float* bproj = (const float*)d_in[5];
  const float* ln2g  = (const float*)d_in[6];
  const float* ln2b  = (const float*)d_in[7];
  const float* W1    = (const float*)d_in[8];
  const float* b1    = (const float*)d_in[9];
  const float* W2    = (const float*)d_in[10];
  const float* b2    = (const float*)d_in[11];
  float* out = (float*)d_out;

  unsigned char* base = (unsigned char*)d_ws;
  size_t off = 0;
  auto alloc = [&](size_t bytes) -> void* {
    off = (off + 255) & ~(size_t)255;
    void* p = base + off;
    off += bytes;
    return p;
  };
  // Transposed bf16 weights [N][K]
  unsigned short* WqkvT  = (unsigned short*)alloc((size_t)(3*CC)*CC*2);
  unsigned short* WprojT = (unsigned short*)alloc((size_t)CC*CC*2);
  unsigned short* W1T    = (unsigned short*)alloc((size_t)HIDN*CC*2);
  unsigned short* W2T    = (unsigned short*)alloc((size_t)CC*HIDN*2);
  float* q0   = (float*)alloc((size_t)BB*CC*4);
  float* wv   = (float*)alloc((size_t)BB*CC*4);
  float* sc   = (float*)alloc((size_t)BB*NPATCH*4);
  int*   tok  = (int*)alloc((size_t)BB*NP*4);
  unsigned short* hbuf = (unsigned short*)alloc((size_t)MRP*CC*2);  // padded rows for 256-tile A-reads
  float* xk   = (float*)alloc((size_t)MR*CC*4);                     // dead after proj-GEMM
  unsigned short* qkv2 = (unsigned short*)alloc((size_t)MRP*3*CC*2);// padded; dead after attention
  if (off > ws_size) return;  // clean fail (no fault) if workspace too small

  unsigned short* obuf = hbuf;                 // alias: ln1-out dead when attn writes
  unsigned short* mid  = (unsigned short*)xk;  // alias: xk+qkv2 region (174.6 MB >= 140.0 MB padded)
  float* x2 = out;                             // residual stream 2 lives in d_out

  // weights: fused transpose + cvt  (in [K][N] f32 -> out [N][K] bf16)
  tcvt_kernel<<<dim3((3*CC)/64, CC/64), 256, 0, stream>>>(Wqkv,  WqkvT,  CC, 3*CC);
  tcvt_kernel<<<dim3(CC/64, CC/64),     256, 0, stream>>>(Wproj, WprojT, CC, CC);
  tcvt_kernel<<<dim3(HIDN/64, CC/64),   256, 0, stream>>>(W1,    W1T,    CC, HIDN);
  tcvt_kernel<<<dim3(CC/64, HIDN/64),   256, 0, stream>>>(W2,    W2T,    HIDN, CC);

  // scoring + selection + gather
  q0_kernel<<<dim3(BB, 3), 256, 0, stream>>>(x, Wqkv, q0);
  wvec_kernel<<<dim3(BB, CC/4), 256, 0, stream>>>(Wqkv, q0, wv);
  score_kernel<<<dim3(NPATCH, BB), 64, 0, stream>>>(x, wv, sc);
  select_kernel<<<BB, 256, 0, stream>>>(sc, tok);
  gather_kernel<<<dim3(NP, BB), 256, 0, stream>>>(x, tok, xk);

  // attention block
  ln_kernel<<<MR, 256, 0, stream>>>(xk, ln1g, ln1b, hbuf);
  gemm256<0><<<(MRP/256)*((3*CC)/256), 512, 0, stream>>>(hbuf, WqkvT, nullptr, nullptr, qkv2, MR, 3*CC, CC);
  attn_kernel<<<dim3(3, HH, BB), 256, 0, stream>>>(qkv2, obuf);
  gemm256<1><<<(MRP/256)*(CC/256), 512, 0, stream>>>(obuf, WprojT, bproj, xk, x2, MR, CC, CC);

  // MLP block
  ln_kernel<<<MR, 256, 0, stream>>>(x2, ln2g, ln2b, hbuf);
  gemm256<2><<<(MRP/256)*(HIDN/256), 512, 0, stream>>>(hbuf, W1T, b1, nullptr, mid, MR, HIDN, CC);
  gemm256<3><<<(MRP/256)*(CC/256), 512, 0, stream>>>(mid, W2T, b2, x2, out, MR, CC, HIDN);
}

// Round 8
// 844.142 us; speedup vs baseline: 1.1450x; 1.1450x over previous
//
#include <hip/hip_runtime.h>
#include <math.h>

#define BB 128
#define NTOK 197
#define CC 768
#define HH 12
#define HD 64
#define HIDN 3072
#define NP 177
#define NPATCH 196
#define THRK 19
#define MR (BB*NP)   // 22656 rows = 177*128

using short8 = __attribute__((ext_vector_type(8))) short;
using f32x4  = __attribute__((ext_vector_type(4))) float;

__device__ __forceinline__ unsigned short f2b(float f){
  unsigned u = __builtin_bit_cast(unsigned, f);
  u += 0x7fffu + ((u >> 16) & 1u);
  return (unsigned short)(u >> 16);
}

// gelu(v) = 0.5 v (1 + erf(v/sqrt2)), erf via A&S 7.1.26 (|err|<=1.5e-7) + __expf
// validated R6/R7: absmax unchanged at 0.03125
__device__ __forceinline__ float fast_gelu(float v){
  float u = v * 0.70710678118654752f;
  float a = fabsf(u);
  float t = 1.0f / fmaf(0.3275911f, a, 1.0f);
  float p = fmaf(1.061405429f, t, -1.453152027f);
  p = fmaf(p, t, 1.421413741f);
  p = fmaf(p, t, -0.284496736f);
  p = fmaf(p, t, 0.254829592f);
  p = p * t;
  float e = __expf(-a*a);
  float erfu = copysignf(1.0f - p*e, u);
  return 0.5f * v * (1.0f + erfu);
}

__device__ __forceinline__ void gload16(const void* src, void* lds){
  __builtin_amdgcn_global_load_lds(
      (const __attribute__((address_space(1))) unsigned int*)src,
      (__attribute__((address_space(3))) unsigned int*)lds,
      16, 0, 0);
}

// ---------- fused transpose+cvt: W[K][N] f32 -> Wt[N][K] bf16 ----------
__global__ void tcvt_kernel(const float* __restrict__ in, unsigned short* __restrict__ out, int K, int N){
  __shared__ float tile[64][65];
  int n0 = blockIdx.x*64, k0 = blockIdx.y*64;
  int t = threadIdx.x;
  int r = t >> 6, c = t & 63;
  #pragma unroll
  for (int i = 0; i < 16; ++i)
    tile[r + i*4][c] = in[(size_t)(k0 + r + i*4)*N + n0 + c];
  __syncthreads();
  #pragma unroll
  for (int i = 0; i < 16; ++i)
    out[(size_t)(n0 + r + i*4)*K + k0 + c] = f2b(tile[c][r + i*4]);
}

// ---------- scoring path (fp64 accum: selection boundary must not flip) ----------
__global__ void q0_kernel(const float* __restrict__ x, const float* __restrict__ Wqkv, float* __restrict__ q0){
  int b = blockIdx.x, t = threadIdx.x;
  int c = blockIdx.y*256 + t;
  __shared__ float xs[CC];
  for (int j = t; j < CC; j += 256) xs[j] = x[(size_t)b*NTOK*CC + j];
  __syncthreads();
  double acc = 0.0;
  for (int j = 0; j < CC; ++j) acc = fma((double)xs[j], (double)Wqkv[(size_t)j*(3*CC) + c], acc);
  q0[b*CC + c] = (float)acc;
}

// wave-per-row, lane-strided (coalesced) reads  [validated R5-R7]
__global__ void wvec_kernel(const float* __restrict__ Wqkv, const float* __restrict__ q0, float* __restrict__ wv){
  int b = blockIdx.x;
  int j = blockIdx.y*4 + (threadIdx.x >> 6);
  int l = threadIdx.x & 63;
  const float* row = Wqkv + (size_t)j*(3*CC) + CC;  // Wk column block
  const float* qs = q0 + b*CC;
  double acc = 0.0;
  for (int c = l; c < CC; c += 64) acc = fma((double)row[c], (double)qs[c], acc);
  for (int off = 32; off; off >>= 1) acc += __shfl_down(acc, off);
  if (l == 0) wv[b*CC + j] = (float)acc;
}

__global__ void score_kernel(const float* __restrict__ x, const float* __restrict__ wv, float* __restrict__ sc){
  int m = blockIdx.x, b = blockIdx.y, l = threadIdx.x;  // one wave per (b,m)
  const float* xr = x + ((size_t)b*NTOK + 1 + m)*CC;
  const float* wr = wv + b*CC;
  double acc = 0.0;
  for (int c = l; c < CC; c += 64) acc = fma((double)xr[c], (double)wr[c], acc);
  for (int off = 32; off; off >>= 1) acc += __shfl_down(acc, off);
  if (l == 0) sc[b*NPATCH + m] = (float)(acc * (1.0/12.0));
}

// stable rank (== argsort(argsort) with stable ties), keep rank>19, compact in order
__global__ void select_kernel(const float* __restrict__ sc, int* __restrict__ tok){
  int b = blockIdx.x, t = threadIdx.x;
  __shared__ float s[NPATCH];
  __shared__ int kp[NPATCH];
  for (int m = t; m < NPATCH; m += 256) s[m] = sc[b*NPATCH + m];
  __syncthreads();
  for (int m = t; m < NPATCH; m += 256){
    float v = s[m]; int rank = 0;
    for (int j = 0; j < NPATCH; ++j){
      float u = s[j];
      rank += (u < v) || (u == v && j < m);
    }
    kp[m] = (rank > THRK) ? 1 : 0;
  }
  __syncthreads();
  for (int m = t; m < NPATCH; m += 256){
    if (kp[m]){
      int pos = 0;
      for (int j = 0; j < m; ++j) pos += kp[j];
      tok[b*NP + 1 + pos] = m + 1;
    }
  }
  if (t == 0) tok[b*NP] = 0;
}

__global__ void gather_kernel(const float* __restrict__ x, const int* __restrict__ tok, float* __restrict__ xk){
  int i = blockIdx.x, b = blockIdx.y, t = threadIdx.x;
  int src = tok[b*NP + i];
  const float* xr = x + ((size_t)b*NTOK + src)*CC;
  float* o = xk + ((size_t)b*NP + i)*CC;
  for (int c = t; c < CC; c += 256) o[c] = xr[c] * (1.0f/0.9f);
}

// ---------- LayerNorm: fp32 in -> bf16 out ----------
__global__ void ln_kernel(const float* __restrict__ in, const float* __restrict__ g,
                          const float* __restrict__ bt, unsigned short* __restrict__ out){
  int row = blockIdx.x, t = threadIdx.x;
  const float* xr = in + (size_t)row*CC;
  float v0 = xr[t], v1 = xr[t+256], v2 = xr[t+512];
  float s = v0+v1+v2, ss = v0*v0+v1*v1+v2*v2;
  for (int off = 32; off; off >>= 1){ s += __shfl_down(s, off); ss += __shfl_down(ss, off); }
  __shared__ float red[8];
  int wid = t >> 6, lane = t & 63;
  if (lane == 0){ red[wid] = s; red[4+wid] = ss; }
  __syncthreads();
  if (t == 0){
    float S = red[0]+red[1]+red[2]+red[3], SS = red[4]+red[5]+red[6]+red[7];
    float mean = S * (1.0f/CC);
    float var = SS * (1.0f/CC) - mean*mean;
    red[0] = mean; red[1] = rsqrtf(var + 1e-5f);
  }
  __syncthreads();
  float mean = red[0], rstd = red[1];
  unsigned short* orow = out + (size_t)row*CC;
  orow[t]     = f2b((v0-mean)*rstd*g[t]     + bt[t]);
  orow[t+256] = f2b((v1-mean)*rstd*g[t+256] + bt[t+256]);
  orow[t+512] = f2b((v2-mean)*rstd*g[t+512] + bt[t+512]);
}

// ---------- GEMM: 128x128 tile, BK=32, dbuf global_load_lds (R4-exact structure) ----------
// A [M][K] bf16 row-major, Bt [N][K] bf16 row-major. M%128==0, N%128==0, K%32==0.
// EPI: 0 = plain -> bf16 ; 1/3 = +bias +res -> f32 ; 2 = +bias, gelu -> bf16
template<int EPI>
__global__ __launch_bounds__(256) void gemm128(
    const unsigned short* __restrict__ A, const unsigned short* __restrict__ Bt,
    const float* __restrict__ bias, const float* __restrict__ res, void* __restrict__ outp,
    int M, int N, int K)
{
  __shared__ __align__(16) short As[2][128*32];
  __shared__ __align__(16) short Bs[2][128*32];
  // bijective XCD swizzle (m204): consecutive seq within an XCD chunk share the A-panel
  int nwg = gridDim.x, o = blockIdx.x;
  int q = nwg >> 3, rr = nwg & 7;
  int xcd = o & 7, seq = o >> 3;
  int wg = (xcd < rr) ? xcd*(q+1) + seq : rr*(q+1) + (xcd - rr)*q + seq;
  int nx = N >> 7;
  int m0 = (wg / nx) << 7, n0 = (wg % nx) << 7;

  int t = threadIdx.x, w = t >> 6, l = t & 63;
  int wr = w >> 1, wc = w & 1;
  // staging: lane l covers row +(l>>2), k-chunk (l&3)*8 within a 16-row wave slab
  int srow = w*16 + (l >> 2);
  int sk8  = (l & 3)*8;
  const unsigned short* Abase = A  + (size_t)(m0 + srow)*K + sk8;
  const unsigned short* Bbase = Bt + (size_t)(n0 + srow)*K + sk8;
  f32x4 acc[4][4] = {};

  int nt = K >> 5;
  // prologue: stage tile 0 into buf 0
  #pragma unroll
  for (int j = 0; j < 2; ++j){
    gload16(Abase + (size_t)(j*64)*K, &As[0][(j*64 + w*16)*32]);
    gload16(Bbase + (size_t)(j*64)*K, &Bs[0][(j*64 + w*16)*32]);
  }
  __syncthreads();   // drains vmcnt(0), publishes buf0

  int cur = 0;
  for (int ti = 0; ti < nt; ++ti){
    // issue next-tile loads into buf[cur^1] BEFORE compute (drain happens after MFMA)
    if (ti + 1 < nt){
      int kt = (ti + 1) << 5;
      #pragma unroll
      for (int j = 0; j < 2; ++j){
        gload16(Abase + (size_t)(j*64)*K + kt, &As[cur^1][(j*64 + w*16)*32]);
        gload16(Bbase + (size_t)(j*64)*K + kt, &Bs[cur^1][(j*64 + w*16)*32]);
      }
    }
    short8 af[4], bf[4];
    #pragma unroll
    for (int i = 0; i < 4; ++i){
      af[i] = *reinterpret_cast<const short8*>(&As[cur][(wr*64 + i*16 + (l&15))*32 + (l>>4)*8]);
      bf[i] = *reinterpret_cast<const short8*>(&Bs[cur][(wc*64 + i*16 + (l&15))*32 + (l>>4)*8]);
    }
    #pragma unroll
    for (int i = 0; i < 4; ++i)
      #pragma unroll
      for (int jn = 0; jn < 4; ++jn)
        acc[i][jn] = __builtin_amdgcn_mfma_f32_16x16x32_bf16(af[i], bf[jn], acc[i][jn], 0, 0, 0);
    __syncthreads();   // single vmcnt(0)+barrier per K-step, after the MFMA cluster
    cur ^= 1;
  }

  #pragma unroll
  for (int i = 0; i < 4; ++i)
  #pragma unroll
  for (int jn = 0; jn < 4; ++jn){
    int row = m0 + wr*64 + i*16 + (l>>4)*4;
    int col = n0 + wc*64 + jn*16 + (l&15);
    #pragma unroll
    for (int r = 0; r < 4; ++r){
      float v = acc[i][jn][r];
      if (EPI != 0) v += bias[col];
      if (EPI == 2) v = fast_gelu(v);
      if (EPI == 1 || EPI == 3) v += res[(size_t)(row+r)*N + col];
      if (EPI == 0 || EPI == 2) ((unsigned short*)outp)[(size_t)(row+r)*N + col] = f2b(v);
      else                      ((float*)outp)[(size_t)(row+r)*N + col] = v;
    }
  }
}

// ---------- fused attention: QK^T -> softmax -> PV, per (rowblock, head, batch) ----------
__global__ __launch_bounds__(256) void attn_kernel(const unsigned short* __restrict__ qkv2,
                                                   unsigned short* __restrict__ o)
{
  int rt = blockIdx.x, h = blockIdx.y, b = blockIdx.z;
  int t = threadIdx.x, w = t >> 6, l = t & 63;
  __shared__ short Vt[64*192];       // Vt[d][m], m padded to 192
  __shared__ short P[4][16*192];     // per-wave P strip
  for (int idx = t; idx < NP*8; idx += 256){
    int m = idx >> 3, d0 = (idx & 7)*8;
    short8 v = *reinterpret_cast<const short8*>(qkv2 + (size_t)(b*NP+m)*(3*CC) + 2*CC + h*HD + d0);
    #pragma unroll
    for (int j = 0; j < 8; ++j) Vt[(d0+j)*192 + m] = v[j];
  }
  for (int idx = t; idx < 64*15; idx += 256){
    int d = idx/15, m = NP + idx%15;
    Vt[d*192 + m] = 0;
  }
  __syncthreads();
  int nb = rt*64 + w*16;
  int g = l >> 4, c = l & 15;
  int nq = nb + c; if (nq > NP-1) nq = NP-1;
  const unsigned short* qrow = qkv2 + (size_t)(b*NP+nq)*(3*CC) + h*HD + 8*g;
  short8 aq0 = *reinterpret_cast<const short8*>(qrow);
  short8 aq1 = *reinterpret_cast<const short8*>(qrow + 32);
  f32x4 acc[12];
  #pragma unroll
  for (int ct = 0; ct < 12; ++ct){
    int m = ct*16 + c; if (m > NP-1) m = NP-1;
    const unsigned short* krow = qkv2 + (size_t)(b*NP+m)*(3*CC) + CC + h*HD + 8*g;
    short8 bk0 = *reinterpret_cast<const short8*>(krow);
    short8 bk1 = *reinterpret_cast<const short8*>(krow + 32);
    f32x4 a = {};
    a = __builtin_amdgcn_mfma_f32_16x16x32_bf16(aq0, bk0, a, 0, 0, 0);
    a = __builtin_amdgcn_mfma_f32_16x16x32_bf16(aq1, bk1, a, 0, 0, 0);
    acc[ct] = a;
  }
  float mx[4] = {-INFINITY, -INFINITY, -INFINITY, -INFINITY};
  #pragma unroll
  for (int ct = 0; ct < 12; ++ct){
    bool valid = (ct*16 + c) < NP;
    #pragma unroll
    for (int r = 0; r < 4; ++r){
      float v = valid ? acc[ct][r]*0.125f : -INFINITY;
      acc[ct][r] = v;
      mx[r] = fmaxf(mx[r], v);
    }
  }
  #pragma unroll
  for (int off = 1; off < 16; off <<= 1){
    #pragma unroll
    for (int r = 0; r < 4; ++r) mx[r] = fmaxf(mx[r], __shfl_xor(mx[r], off));
  }
  float sm2[4] = {0.f, 0.f, 0.f, 0.f};
  #pragma unroll
  for (int ct = 0; ct < 12; ++ct)
    #pragma unroll
    for (int r = 0; r < 4; ++r){
      float e = __expf(acc[ct][r] - mx[r]);
      acc[ct][r] = e; sm2[r] += e;
    }
  #pragma unroll
  for (int off = 1; off < 16; off <<= 1){
    #pragma unroll
    for (int r = 0; r < 4; ++r) sm2[r] += __shfl_xor(sm2[r], off);
  }
  float inv[4];
  #pragma unroll
  for (int r = 0; r < 4; ++r) inv[r] = 1.0f / sm2[r];
  #pragma unroll
  for (int ct = 0; ct < 12; ++ct)
    #pragma unroll
    for (int r = 0; r < 4; ++r)
      P[w][(4*g + r)*192 + ct*16 + c] = (short)f2b(acc[ct][r]*inv[r]);
  f32x4 acc2[4] = {};
  __builtin_amdgcn_s_setprio(1);
  #pragma unroll
  for (int ks = 0; ks < 6; ++ks){
    short8 pa = *reinterpret_cast<const short8*>(&P[w][c*192 + ks*32 + 8*g]);
    #pragma unroll
    for (int ct2 = 0; ct2 < 4; ++ct2){
      short8 bv = *reinterpret_cast<const short8*>(&Vt[(ct2*16 + c)*192 + ks*32 + 8*g]);
      acc2[ct2] = __builtin_amdgcn_mfma_f32_16x16x32_bf16(pa, bv, acc2[ct2], 0, 0, 0);
    }
  }
  __builtin_amdgcn_s_setprio(0);
  #pragma unroll
  for (int ct2 = 0; ct2 < 4; ++ct2){
    #pragma unroll
    for (int r = 0; r < 4; ++r){
      int n = nb + 4*g + r;
      if (n < NP) o[(size_t)(b*NP+n)*CC + h*HD + ct2*16 + c] = f2b(acc2[ct2][r]);
    }
  }
}

extern "C" void kernel_launch(void* const* d_in, const int* in_sizes, int n_in,
                              void* d_out, int out_size, void* d_ws, size_t ws_size,
                              hipStream_t stream) {
  const float* x     = (const float*)d_in[0];
  const float* ln1g  = (const float*)d_in[1];
  const float* ln1b  = (const float*)d_in[2];
  const float* Wqkv  = (const float*)d_in[3];
  const float* Wproj = (const float*)d_in[4];
  const float* bproj = (const float*)d_in[5];
  const float* ln2g  = (const float*)d_in[6];
  const float* ln2b  = (const float*)d_in[7];
  const float* W1    = (const float*)d_in[8];
  const float* b1    = (const float*)d_in[9];
  const float* W2    = (const float*)d_in[10];
  const float* b2    = (const float*)d_in[11];
  float* out = (float*)d_out;

  unsigned char* base = (unsigned char*)d_ws;
  size_t off = 0;
  auto alloc = [&](size_t bytes) -> void* {
    off = (off + 255) & ~(size_t)255;
    void* p = base + off;
    off += bytes;
    return p;
  };
  // Transposed bf16 weights [N][K]
  unsigned short* WqkvT  = (unsigned short*)alloc((size_t)(3*CC)*CC*2);
  unsigned short* WprojT = (unsigned short*)alloc((size_t)CC*CC*2);
  unsigned short* W1T    = (unsigned short*)alloc((size_t)HIDN*CC*2);
  unsigned short* W2T    = (unsigned short*)alloc((size_t)CC*HIDN*2);
  float* q0   = (float*)alloc((size_t)BB*CC*4);
  float* wv   = (float*)alloc((size_t)BB*CC*4);
  float* sc   = (float*)alloc((size_t)BB*NPATCH*4);
  int*   tok  = (int*)alloc((size_t)BB*NP*4);
  unsigned short* hbuf = (unsigned short*)alloc((size_t)MR*CC*2);   // ln1-out, then attn-out, then ln2-out
  float* xk   = (float*)alloc((size_t)MR*CC*4);                     // dead after proj-GEMM
  unsigned short* qkv2 = (unsigned short*)alloc((size_t)MR*3*CC*2); // dead after attention
  if (off > ws_size) return;  // clean fail (no fault) if workspace too small

  unsigned short* obuf = hbuf;                 // alias: ln1-out dead when attn writes
  unsigned short* mid  = (unsigned short*)xk;  // alias: xk+qkv2 region (174 MB >= 139.2 MB)
  float* x2 = out;                             // residual stream 2 lives in d_out

  // weights: fused transpose + cvt  (in [K][N] f32 -> out [N][K] bf16)
  tcvt_kernel<<<dim3((3*CC)/64, CC/64), 256, 0, stream>>>(Wqkv,  WqkvT,  CC, 3*CC);
  tcvt_kernel<<<dim3(CC/64, CC/64),     256, 0, stream>>>(Wproj, WprojT, CC, CC);
  tcvt_kernel<<<dim3(HIDN/64, CC/64),   256, 0, stream>>>(W1,    W1T,    CC, HIDN);
  tcvt_kernel<<<dim3(CC/64, HIDN/64),   256, 0, stream>>>(W2,    W2T,    HIDN, CC);

  // scoring + selection + gather
  q0_kernel<<<dim3(BB, 3), 256, 0, stream>>>(x, Wqkv, q0);
  wvec_kernel<<<dim3(BB, CC/4), 256, 0, stream>>>(Wqkv, q0, wv);
  score_kernel<<<dim3(NPATCH, BB), 64, 0, stream>>>(x, wv, sc);
  select_kernel<<<BB, 256, 0, stream>>>(sc, tok);
  gather_kernel<<<dim3(NP, BB), 256, 0, stream>>>(x, tok, xk);

  // attention block
  ln_kernel<<<MR, 256, 0, stream>>>(xk, ln1g, ln1b, hbuf);
  gemm128<0><<<(MR/128)*((3*CC)/128), 256, 0, stream>>>(hbuf, WqkvT, nullptr, nullptr, qkv2, MR, 3*CC, CC);
  attn_kernel<<<dim3(3, HH, BB), 256, 0, stream>>>(qkv2, obuf);
  gemm128<1><<<(MR/128)*(CC/128), 256, 0, stream>>>(obuf, WprojT, bproj, xk, x2, MR, CC, CC);

  // MLP block
  ln_kernel<<<MR, 256, 0, stream>>>(x2, ln2g, ln2b, hbuf);
  gemm128<2><<<(MR/128)*(HIDN/128), 256, 0, stream>>>(hbuf, W1T, b1, nullptr, mid, MR, HIDN, CC);
  gemm128<3><<<(MR/128)*(CC/128), 256, 0, stream>>>(mid, W2T, b2, x2, out, MR, CC, HIDN);
}

// Round 9
// 767.219 us; speedup vs baseline: 1.2598x; 1.1003x over previous
//
#include <hip/hip_runtime.h>
#include <math.h>

#define BB 128
#define NTOK 197
#define CC 768
#define HH 12
#define HD 64
#define HIDN 3072
#define NP 177
#define NPATCH 196
#define THRK 19
#define MR (BB*NP)   // 22656 rows = 177*128

using short8 = __attribute__((ext_vector_type(8))) short;
using f32x4  = __attribute__((ext_vector_type(4))) float;

__device__ __forceinline__ unsigned short f2b(float f){
  unsigned u = __builtin_bit_cast(unsigned, f);
  u += 0x7fffu + ((u >> 16) & 1u);
  return (unsigned short)(u >> 16);
}

// gelu via A&S 7.1.26 erf (|err|<=1.5e-7); validated R6-R8, absmax unchanged
__device__ __forceinline__ float fast_gelu(float v){
  float u = v * 0.70710678118654752f;
  float a = fabsf(u);
  float t = 1.0f / fmaf(0.3275911f, a, 1.0f);
  float p = fmaf(1.061405429f, t, -1.453152027f);
  p = fmaf(p, t, 1.421413741f);
  p = fmaf(p, t, -0.284496736f);
  p = fmaf(p, t, 0.254829592f);
  p = p * t;
  float e = __expf(-a*a);
  float erfu = copysignf(1.0f - p*e, u);
  return 0.5f * v * (1.0f + erfu);
}

__device__ __forceinline__ void gload16(const void* src, void* lds){
  __builtin_amdgcn_global_load_lds(
      (const __attribute__((address_space(1))) unsigned int*)src,
      (__attribute__((address_space(3))) unsigned int*)lds,
      16, 0, 0);
}

// ---------- fused transpose+cvt: W[K][N] f32 -> Wt[N][K] bf16 ----------
__global__ void tcvt_kernel(const float* __restrict__ in, unsigned short* __restrict__ out, int K, int N){
  __shared__ float tile[64][65];
  int n0 = blockIdx.x*64, k0 = blockIdx.y*64;
  int t = threadIdx.x;
  int r = t >> 6, c = t & 63;
  #pragma unroll
  for (int i = 0; i < 16; ++i)
    tile[r + i*4][c] = in[(size_t)(k0 + r + i*4)*N + n0 + c];
  __syncthreads();
  #pragma unroll
  for (int i = 0; i < 16; ++i)
    out[(size_t)(n0 + r + i*4)*K + k0 + c] = f2b(tile[c][r + i*4]);
}

// ---------- scoring path (fp64 accum: selection boundary must not flip) ----------
__global__ void q0_kernel(const float* __restrict__ x, const float* __restrict__ Wqkv, float* __restrict__ q0){
  int b = blockIdx.x, t = threadIdx.x;
  int c = blockIdx.y*256 + t;
  __shared__ float xs[CC];
  for (int j = t; j < CC; j += 256) xs[j] = x[(size_t)b*NTOK*CC + j];
  __syncthreads();
  double acc = 0.0;
  for (int j = 0; j < CC; ++j) acc = fma((double)xs[j], (double)Wqkv[(size_t)j*(3*CC) + c], acc);
  q0[b*CC + c] = (float)acc;
}

// wave-per-row, lane-strided (coalesced) reads  [validated R5-R8]
__global__ void wvec_kernel(const float* __restrict__ Wqkv, const float* __restrict__ q0, float* __restrict__ wv){
  int b = blockIdx.x;
  int j = blockIdx.y*4 + (threadIdx.x >> 6);
  int l = threadIdx.x & 63;
  const float* row = Wqkv + (size_t)j*(3*CC) + CC;  // Wk column block
  const float* qs = q0 + b*CC;
  double acc = 0.0;
  for (int c = l; c < CC; c += 64) acc = fma((double)row[c], (double)qs[c], acc);
  for (int off = 32; off; off >>= 1) acc += __shfl_down(acc, off);
  if (l == 0) wv[b*CC + j] = (float)acc;
}

__global__ void score_kernel(const float* __restrict__ x, const float* __restrict__ wv, float* __restrict__ sc){
  int m = blockIdx.x, b = blockIdx.y, l = threadIdx.x;  // one wave per (b,m)
  const float* xr = x + ((size_t)b*NTOK + 1 + m)*CC;
  const float* wr = wv + b*CC;
  double acc = 0.0;
  for (int c = l; c < CC; c += 64) acc = fma((double)xr[c], (double)wr[c], acc);
  for (int off = 32; off; off >>= 1) acc += __shfl_down(acc, off);
  if (l == 0) sc[b*NPATCH + m] = (float)(acc * (1.0/12.0));
}

// stable rank (== argsort(argsort) with stable ties), keep rank>19, compact in order
__global__ void select_kernel(const float* __restrict__ sc, int* __restrict__ tok){
  int b = blockIdx.x, t = threadIdx.x;
  __shared__ float s[NPATCH];
  __shared__ int kp[NPATCH];
  for (int m = t; m < NPATCH; m += 256) s[m] = sc[b*NPATCH + m];
  __syncthreads();
  for (int m = t; m < NPATCH; m += 256){
    float v = s[m]; int rank = 0;
    for (int j = 0; j < NPATCH; ++j){
      float u = s[j];
      rank += (u < v) || (u == v && j < m);
    }
    kp[m] = (rank > THRK) ? 1 : 0;
  }
  __syncthreads();
  for (int m = t; m < NPATCH; m += 256){
    if (kp[m]){
      int pos = 0;
      for (int j = 0; j < m; ++j) pos += kp[j];
      tok[b*NP + 1 + pos] = m + 1;
    }
  }
  if (t == 0) tok[b*NP] = 0;
}

__global__ void gather_kernel(const float* __restrict__ x, const int* __restrict__ tok, float* __restrict__ xk){
  int i = blockIdx.x, b = blockIdx.y, t = threadIdx.x;
  int src = tok[b*NP + i];
  const float* xr = x + ((size_t)b*NTOK + src)*CC;
  float* o = xk + ((size_t)b*NP + i)*CC;
  for (int c = t; c < CC; c += 256) o[c] = xr[c] * (1.0f/0.9f);
}

// ---------- LayerNorm: fp32 in -> bf16 out ----------
__global__ void ln_kernel(const float* __restrict__ in, const float* __restrict__ g,
                          const float* __restrict__ bt, unsigned short* __restrict__ out){
  int row = blockIdx.x, t = threadIdx.x;
  const float* xr = in + (size_t)row*CC;
  float v0 = xr[t], v1 = xr[t+256], v2 = xr[t+512];
  float s = v0+v1+v2, ss = v0*v0+v1*v1+v2*v2;
  for (int off = 32; off; off >>= 1){ s += __shfl_down(s, off); ss += __shfl_down(ss, off); }
  __shared__ float red[8];
  int wid = t >> 6, lane = t & 63;
  if (lane == 0){ red[wid] = s; red[4+wid] = ss; }
  __syncthreads();
  if (t == 0){
    float S = red[0]+red[1]+red[2]+red[3], SS = red[4]+red[5]+red[6]+red[7];
    float mean = S * (1.0f/CC);
    float var = SS * (1.0f/CC) - mean*mean;
    red[0] = mean; red[1] = rsqrtf(var + 1e-5f);
  }
  __syncthreads();
  float mean = red[0], rstd = red[1];
  unsigned short* orow = out + (size_t)row*CC;
  orow[t]     = f2b((v0-mean)*rstd*g[t]     + bt[t]);
  orow[t+256] = f2b((v1-mean)*rstd*g[t+256] + bt[t+256]);
  orow[t+512] = f2b((v2-mean)*rstd*g[t+512] + bt[t+512]);
}

// ---------- GEMM: 128x128 tile, BK=32, 3-buffer counted-vmcnt + XOR swizzle ----------
// A [M][K] bf16 row-major, Bt [N][K] bf16 row-major. M%128==0, N%128==0, K%96==0 (nt%3==0).
// Schedule (R7-validated sync): stage 2 tiles ahead into 3 rotating buffers; per step
// s_waitcnt vmcnt(4) (leaves next-next tile's 4 loads in flight) + raw s_barrier.
// Swizzle (R7-validated, 0 bank conflicts): LDS slot k16 at row r holds global chunk
// k16^((r>>1)&3); gload dest lane-linear, source inverse-swizzled, ds_read swizzled.
// EPI: 0 = plain -> bf16 ; 1/3 = +bias +res -> f32 ; 2 = +bias, gelu -> bf16
template<int EPI>
__global__ __launch_bounds__(256, 3) void gemm128(
    const unsigned short* __restrict__ A, const unsigned short* __restrict__ Bt,
    const float* __restrict__ bias, const float* __restrict__ res, void* __restrict__ outp,
    int M, int N, int K)
{
  __shared__ __align__(16) short lds[3*8192];   // per buf: A 4096 shorts, B 4096 shorts
  // bijective XCD swizzle (m204)
  int nwg = gridDim.x, o = blockIdx.x;
  int q = nwg >> 3, rr = nwg & 7;
  int xcd = o & 7, seq = o >> 3;
  int wg = (xcd < rr) ? xcd*(q+1) + seq : rr*(q+1) + (xcd - rr)*q + seq;
  int nx = N >> 7;
  int m0 = (wg / nx) << 7, n0 = (wg % nx) << 7;

  int t = threadIdx.x, w = t >> 6, l = t & 63;
  int wr = w >> 1, wc = w & 1;
  f32x4 acc[4][4] = {};
  int nt = K >> 5;

  auto stage = [&](int kti, int sb){
    int kt = kti << 5;
    short* buf = &lds[sb*8192];
    #pragma unroll
    for (int j = 0; j < 2; ++j){
      int row = j*64 + w*16 + (l >> 2);                  // tile row this lane covers
      int gk = ((l & 3) ^ ((row >> 1) & 3)) * 8;         // inverse-swizzled source chunk
      gload16(A  + (size_t)(m0 + row)*K + kt + gk, &buf[(j*64 + w*16)*32]);
      gload16(Bt + (size_t)(n0 + row)*K + kt + gk, &buf[4096 + (j*64 + w*16)*32]);
    }
  };
  auto compute = [&](int cb){
    const short* Ab = &lds[cb*8192];
    const short* Bb = Ab + 4096;
    short8 af[4], bf[4];
    #pragma unroll
    for (int i = 0; i < 4; ++i){
      int Ra = wr*64 + i*16 + (l & 15);
      af[i] = *reinterpret_cast<const short8*>(&Ab[Ra*32 + (((l>>4) ^ ((Ra>>1)&3)))*8]);
      int Rb = wc*64 + i*16 + (l & 15);
      bf[i] = *reinterpret_cast<const short8*>(&Bb[Rb*32 + (((l>>4) ^ ((Rb>>1)&3)))*8]);
    }
    __builtin_amdgcn_s_setprio(1);
    #pragma unroll
    for (int i = 0; i < 4; ++i)
      #pragma unroll
      for (int jn = 0; jn < 4; ++jn)
        acc[i][jn] = __builtin_amdgcn_mfma_f32_16x16x32_bf16(af[i], bf[jn], acc[i][jn], 0, 0, 0);
    __builtin_amdgcn_s_setprio(0);
  };
  auto step = [&](int ti, int cb, int sb){
    bool more = (ti + 2) < nt;
    if (more) stage(ti + 2, sb);
    compute(cb);
    if (more) asm volatile("s_waitcnt vmcnt(4)" ::: "memory");  // next tile landed; next-next in flight
    else      asm volatile("s_waitcnt vmcnt(0)" ::: "memory");
    __builtin_amdgcn_s_barrier();
    asm volatile("" ::: "memory");
  };

  // prologue: tiles 0,1 in flight; vmcnt(4) confirms tile 0, leaves tile 1 flying
  stage(0, 0); stage(1, 1);
  asm volatile("s_waitcnt vmcnt(4)" ::: "memory");
  __builtin_amdgcn_s_barrier();
  asm volatile("" ::: "memory");

  #pragma unroll 1
  for (int ti = 0; ti < nt; ti += 3){   // nt = 24 or 96, divisible by 3
    step(ti,     0, 2);
    step(ti + 1, 1, 0);
    step(ti + 2, 2, 1);
  }

  #pragma unroll
  for (int i = 0; i < 4; ++i)
  #pragma unroll
  for (int jn = 0; jn < 4; ++jn){
    int row = m0 + wr*64 + i*16 + (l>>4)*4;
    int col = n0 + wc*64 + jn*16 + (l&15);
    #pragma unroll
    for (int r = 0; r < 4; ++r){
      float v = acc[i][jn][r];
      if (EPI != 0) v += bias[col];
      if (EPI == 2) v = fast_gelu(v);
      if (EPI == 1 || EPI == 3) v += res[(size_t)(row+r)*N + col];
      if (EPI == 0 || EPI == 2) ((unsigned short*)outp)[(size_t)(row+r)*N + col] = f2b(v);
      else                      ((float*)outp)[(size_t)(row+r)*N + col] = v;
    }
  }
}

// ---------- fused attention: QK^T -> softmax -> PV, per (rowblock, head, batch) ----------
__global__ __launch_bounds__(256) void attn_kernel(const unsigned short* __restrict__ qkv2,
                                                   unsigned short* __restrict__ o)
{
  int rt = blockIdx.x, h = blockIdx.y, b = blockIdx.z;
  int t = threadIdx.x, w = t >> 6, l = t & 63;
  __shared__ short Vt[64*192];       // Vt[d][m], m padded to 192
  __shared__ short P[4][16*192];     // per-wave P strip
  for (int idx = t; idx < NP*8; idx += 256){
    int m = idx >> 3, d0 = (idx & 7)*8;
    short8 v = *reinterpret_cast<const short8*>(qkv2 + (size_t)(b*NP+m)*(3*CC) + 2*CC + h*HD + d0);
    #pragma unroll
    for (int j = 0; j < 8; ++j) Vt[(d0+j)*192 + m] = v[j];
  }
  for (int idx = t; idx < 64*15; idx += 256){
    int d = idx/15, m = NP + idx%15;
    Vt[d*192 + m] = 0;
  }
  __syncthreads();
  int nb = rt*64 + w*16;
  int g = l >> 4, c = l & 15;
  int nq = nb + c; if (nq > NP-1) nq = NP-1;
  const unsigned short* qrow = qkv2 + (size_t)(b*NP+nq)*(3*CC) + h*HD + 8*g;
  short8 aq0 = *reinterpret_cast<const short8*>(qrow);
  short8 aq1 = *reinterpret_cast<const short8*>(qrow + 32);
  f32x4 acc[12];
  #pragma unroll
  for (int ct = 0; ct < 12; ++ct){
    int m = ct*16 + c; if (m > NP-1) m = NP-1;
    const unsigned short* krow = qkv2 + (size_t)(b*NP+m)*(3*CC) + CC + h*HD + 8*g;
    short8 bk0 = *reinterpret_cast<const short8*>(krow);
    short8 bk1 = *reinterpret_cast<const short8*>(krow + 32);
    f32x4 a = {};
    a = __builtin_amdgcn_mfma_f32_16x16x32_bf16(aq0, bk0, a, 0, 0, 0);
    a = __builtin_amdgcn_mfma_f32_16x16x32_bf16(aq1, bk1, a, 0, 0, 0);
    acc[ct] = a;
  }
  float mx[4] = {-INFINITY, -INFINITY, -INFINITY, -INFINITY};
  #pragma unroll
  for (int ct = 0; ct < 12; ++ct){
    bool valid = (ct*16 + c) < NP;
    #pragma unroll
    for (int r = 0; r < 4; ++r){
      float v = valid ? acc[ct][r]*0.125f : -INFINITY;
      acc[ct][r] = v;
      mx[r] = fmaxf(mx[r], v);
    }
  }
  #pragma unroll
  for (int off = 1; off < 16; off <<= 1){
    #pragma unroll
    for (int r = 0; r < 4; ++r) mx[r] = fmaxf(mx[r], __shfl_xor(mx[r], off));
  }
  float sm2[4] = {0.f, 0.f, 0.f, 0.f};
  #pragma unroll
  for (int ct = 0; ct < 12; ++ct)
    #pragma unroll
    for (int r = 0; r < 4; ++r){
      float e = __expf(acc[ct][r] - mx[r]);
      acc[ct][r] = e; sm2[r] += e;
    }
  #pragma unroll
  for (int off = 1; off < 16; off <<= 1){
    #pragma unroll
    for (int r = 0; r < 4; ++r) sm2[r] += __shfl_xor(sm2[r], off);
  }
  float inv[4];
  #pragma unroll
  for (int r = 0; r < 4; ++r) inv[r] = 1.0f / sm2[r];
  #pragma unroll
  for (int ct = 0; ct < 12; ++ct)
    #pragma unroll
    for (int r = 0; r < 4; ++r)
      P[w][(4*g + r)*192 + ct*16 + c] = (short)f2b(acc[ct][r]*inv[r]);
  f32x4 acc2[4] = {};
  __builtin_amdgcn_s_setprio(1);
  #pragma unroll
  for (int ks = 0; ks < 6; ++ks){
    short8 pa = *reinterpret_cast<const short8*>(&P[w][c*192 + ks*32 + 8*g]);
    #pragma unroll
    for (int ct2 = 0; ct2 < 4; ++ct2){
      short8 bv = *reinterpret_cast<const short8*>(&Vt[(ct2*16 + c)*192 + ks*32 + 8*g]);
      acc2[ct2] = __builtin_amdgcn_mfma_f32_16x16x32_bf16(pa, bv, acc2[ct2], 0, 0, 0);
    }
  }
  __builtin_amdgcn_s_setprio(0);
  #pragma unroll
  for (int ct2 = 0; ct2 < 4; ++ct2){
    #pragma unroll
    for (int r = 0; r < 4; ++r){
      int n = nb + 4*g + r;
      if (n < NP) o[(size_t)(b*NP+n)*CC + h*HD + ct2*16 + c] = f2b(acc2[ct2][r]);
    }
  }
}

extern "C" void kernel_launch(void* const* d_in, const int* in_sizes, int n_in,
                              void* d_out, int out_size, void* d_ws, size_t ws_size,
                              hipStream_t stream) {
  const float* x     = (const float*)d_in[0];
  const float* ln1g  = (const float*)d_in[1];
  const float* ln1b  = (const float*)d_in[2];
  const float* Wqkv  = (const float*)d_in[3];
  const float* Wproj = (const float*)d_in[4];
  const float* bproj = (const float*)d_in[5];
  const float* ln2g  = (const float*)d_in[6];
  const float* ln2b  = (const float*)d_in[7];
  const float* W1    = (const float*)d_in[8];
  const float* b1    = (const float*)d_in[9];
  const float* W2    = (const float*)d_in[10];
  const float* b2    = (const float*)d_in[11];
  float* out = (float*)d_out;

  unsigned char* base = (unsigned char*)d_ws;
  size_t off = 0;
  auto alloc = [&](size_t bytes) -> void* {
    off = (off + 255) & ~(size_t)255;
    void* p = base + off;
    off += bytes;
    return p;
  };
  // Transposed bf16 weights [N][K]
  unsigned short* WqkvT  = (unsigned short*)alloc((size_t)(3*CC)*CC*2);
  unsigned short* WprojT = (unsigned short*)alloc((size_t)CC*CC*2);
  unsigned short* W1T    = (unsigned short*)alloc((size_t)HIDN*CC*2);
  unsigned short* W2T    = (unsigned short*)alloc((size_t)CC*HIDN*2);
  float* q0   = (float*)alloc((size_t)BB*CC*4);
  float* wv   = (float*)alloc((size_t)BB*CC*4);
  float* sc   = (float*)alloc((size_t)BB*NPATCH*4);
  int*   tok  = (int*)alloc((size_t)BB*NP*4);
  unsigned short* hbuf = (unsigned short*)alloc((size_t)MR*CC*2);   // ln1-out, then attn-out, then ln2-out
  float* xk   = (float*)alloc((size_t)MR*CC*4);                     // dead after proj-GEMM
  unsigned short* qkv2 = (unsigned short*)alloc((size_t)MR*3*CC*2); // dead after attention
  if (off > ws_size) return;  // clean fail (no fault) if workspace too small

  unsigned short* obuf = hbuf;                 // alias: ln1-out dead when attn writes
  unsigned short* mid  = (unsigned short*)xk;  // alias: xk+qkv2 region (174 MB >= 139.2 MB)
  float* x2 = out;                             // residual stream 2 lives in d_out

  // weights: fused transpose + cvt  (in [K][N] f32 -> out [N][K] bf16)
  tcvt_kernel<<<dim3((3*CC)/64, CC/64), 256, 0, stream>>>(Wqkv,  WqkvT,  CC, 3*CC);
  tcvt_kernel<<<dim3(CC/64, CC/64),     256, 0, stream>>>(Wproj, WprojT, CC, CC);
  tcvt_kernel<<<dim3(HIDN/64, CC/64),   256, 0, stream>>>(W1,    W1T,    CC, HIDN);
  tcvt_kernel<<<dim3(CC/64, HIDN/64),   256, 0, stream>>>(W2,    W2T,    HIDN, CC);

  // scoring + selection + gather
  q0_kernel<<<dim3(BB, 3), 256, 0, stream>>>(x, Wqkv, q0);
  wvec_kernel<<<dim3(BB, CC/4), 256, 0, stream>>>(Wqkv, q0, wv);
  score_kernel<<<dim3(NPATCH, BB), 64, 0, stream>>>(x, wv, sc);
  select_kernel<<<BB, 256, 0, stream>>>(sc, tok);
  gather_kernel<<<dim3(NP, BB), 256, 0, stream>>>(x, tok, xk);

  // attention block
  ln_kernel<<<MR, 256, 0, stream>>>(xk, ln1g, ln1b, hbuf);
  gemm128<0><<<(MR/128)*((3*CC)/128), 256, 0, stream>>>(hbuf, WqkvT, nullptr, nullptr, qkv2, MR, 3*CC, CC);
  attn_kernel<<<dim3(3, HH, BB), 256, 0, stream>>>(qkv2, obuf);
  gemm128<1><<<(MR/128)*(CC/128), 256, 0, stream>>>(obuf, WprojT, bproj, xk, x2, MR, CC, CC);

  // MLP block
  ln_kernel<<<MR, 256, 0, stream>>>(x2, ln2g, ln2b, hbuf);
  gemm128<2><<<(MR/128)*(HIDN/128), 256, 0, stream>>>(hbuf, W1T, b1, nullptr, mid, MR, HIDN, CC);
  gemm128<3><<<(MR/128)*(CC/128), 256, 0, stream>>>(mid, W2T, b2, x2, out, MR, CC, HIDN);
}